// Round 1
// 555.397 us; speedup vs baseline: 1.1351x; 1.1351x over previous
//
#include <hip/hip_runtime.h>
#include <hip/hip_bf16.h>
#include <cstddef>
#include <cstdint>

#define N_USER 100000
#define N_ITEM 100000
#define N_EDGE 1000000
#define IN_DIM 256
#define HID 128
#define OUT_DIM 16
#define LEAKY_SLOPE 0.01f
#define NBKT 6250        // 100000 / 16 dst rows per bucket
#define SCAN_BLK 25      // ceil(6250/256)
#define SRC_MASK 0x07FFFFFFu

typedef __attribute__((ext_vector_type(8))) short bf16x8;
typedef __attribute__((ext_vector_type(4))) float f32x4;

static __device__ __forceinline__ unsigned short f2bf(float f) {
  // RTNE bf16 (matches __float2bfloat16 for normal values)
  unsigned int u = __float_as_uint(f);
  u = (u + 0x7FFFu + ((u >> 16) & 1u)) >> 16;
  return (unsigned short)u;
}

// ---------------------------------------------------------------------------
// split fp32 -> (hi, lo) bf16: a ~= hi + lo with ~16-bit effective mantissa.
// hi = truncate-to-bf16(a) (exact residual), lo = truncate-to-bf16(a - hi).
// ---------------------------------------------------------------------------
static __device__ __forceinline__ void split8(const float4 x, const float4 y,
                                              bf16x8& hi, bf16x8& lo) {
  const float f[8] = {x.x, x.y, x.z, x.w, y.x, y.y, y.z, y.w};
#pragma unroll
  for (int j = 0; j < 8; ++j) {
    const unsigned u = __float_as_uint(f[j]);
    hi[j] = (short)(u >> 16);
    const float lf = f[j] - __uint_as_float(u & 0xffff0000u);
    lo[j] = (short)(__float_as_uint(lf) >> 16);
  }
}

// ---------------------------------------------------------------------------
// Build fused layer-0 weight Wf0 = Win_user @ W0_clicks [256,128], pre-SPLIT
// into (hi,lo) bf16 and pre-SWIZZLED into MFMA B-fragment order, plus
// bf0 = bin_user @ W0_clicks + b0_clicks.
// Bswz layout (ushort): [(kt*16 + nf*2 + s)*512 + lane*8 + j]
//   kt = k>>5 (k-step of 32), lane = ((k>>3)&3)*16 + (n&15), j = k&7, nf = n>>4
// ---------------------------------------------------------------------------
__global__ __launch_bounds__(256)
void make_wfuse0(const float* __restrict__ Win, const float* __restrict__ bin,
                 const float* __restrict__ W0, const float* __restrict__ b0,
                 unsigned short* __restrict__ Bswz, float* __restrict__ bf0) {
  const int t = threadIdx.x;
  const int r = blockIdx.x * 2 + (t >> 7);   // k index in [0,256)
  const int n = t & 127;                     // col in [0,128)
  const float* wr = Win + (size_t)r * HID;
  float s = 0.f;
#pragma unroll 8
  for (int m = 0; m < HID; ++m) s += wr[m] * W0[(size_t)m * HID + n];
  const unsigned u = __float_as_uint(s);
  const unsigned short hi = (unsigned short)(u >> 16);
  const float lf = s - __uint_as_float(u & 0xffff0000u);
  const unsigned short lo = (unsigned short)(__float_as_uint(lf) >> 16);
  const int kt = r >> 5, lh = (r >> 3) & 3, j = r & 7;
  const int nf = n >> 4, lane = lh * 16 + (n & 15);
  Bswz[(size_t)(kt * 16 + nf * 2) * 512 + lane * 8 + j] = hi;
  Bswz[(size_t)(kt * 16 + nf * 2 + 1) * 512 + lane * 8 + j] = lo;
  if (blockIdx.x == 0 && t < HID) {
    float s2 = b0[t];
    for (int m = 0; m < HID; ++m) s2 += bin[m] * W0[(size_t)m * HID + t];
    bf0[t] = s2;
  }
}

// ---------------------------------------------------------------------------
// Wh[M,128](bf16) = A[M,256](fp32) @ Wf0 + bf0 via split-bf16 MFMA.
// Block = 256 thr (4 waves), BM=128 (32 rows/wave = 2 row-frags), full N=128.
// B (pre-swizzled frags) double-buffered in LDS per K-chunk of 64;
// A loaded global->reg (each element exactly once), prefetched 1 chunk ahead.
// 3 MFMAs per frag pair: ah*bh + ah*bl + al*bh  (error ~2^-16 rel ~ fp32).
// ---------------------------------------------------------------------------
__global__ __launch_bounds__(256, 2)
void gemm_feat_mfma(const float* __restrict__ A,
                    const unsigned short* __restrict__ Bswz,
                    const float* __restrict__ bias,
                    unsigned short* __restrict__ Wh, int M) {
  __shared__ unsigned short Bs[2][16384];   // 2 x 32 KB
  const int t = threadIdx.x;
  const int w = t >> 6, lane = t & 63;
  const int rowW = blockIdx.x * 128 + w * 32;
  const int lr = lane & 15;                 // row-in-frag / col-in-frag
  const int lk = (lane >> 4) << 3;          // k offset 0/8/16/24

  int r0 = rowW + lr;      if (r0 >= M) r0 = M - 1;
  int r1 = rowW + 16 + lr; if (r1 >= M) r1 = M - 1;
  const float* pa0 = A + (size_t)r0 * IN_DIM + lk;
  const float* pa1 = A + (size_t)r1 * IN_DIM + lk;

  float bv[8];
#pragma unroll
  for (int nf = 0; nf < 8; ++nf) bv[nf] = bias[nf * 16 + lr];

  f32x4 acc[2][8];
#pragma unroll
  for (int rf = 0; rf < 2; ++rf)
#pragma unroll
    for (int nf = 0; nf < 8; ++nf)
#pragma unroll
      for (int q = 0; q < 4; ++q) acc[rf][nf][q] = 0.f;

  float4 af[2][2][2][2];  // [buf][rf][ktl][half]

#define STAGE_B(c, buf)                                                        \
  {                                                                            \
    _Pragma("unroll")                                                          \
    for (int i = 0; i < 8; ++i)                                                \
      __builtin_amdgcn_global_load_lds(                                        \
          (const __attribute__((address_space(1))) unsigned int*)              \
              ((const char*)Bswz + (c) * 32768 + i * 4096 + t * 16),           \
          (__attribute__((address_space(3))) unsigned int*)                    \
              &Bs[buf][i * 2048 + w * 512],                                    \
          16, 0, 0);                                                           \
  }

#define LOAD_A(c, buf)                                                         \
  {                                                                            \
    _Pragma("unroll")                                                          \
    for (int ktl = 0; ktl < 2; ++ktl) {                                        \
      af[buf][0][ktl][0] = *(const float4*)(pa0 + (c) * 64 + ktl * 32);        \
      af[buf][0][ktl][1] = *(const float4*)(pa0 + (c) * 64 + ktl * 32 + 4);    \
      af[buf][1][ktl][0] = *(const float4*)(pa1 + (c) * 64 + ktl * 32);        \
      af[buf][1][ktl][1] = *(const float4*)(pa1 + (c) * 64 + ktl * 32 + 4);    \
    }                                                                          \
  }

  STAGE_B(0, 0)
  LOAD_A(0, 0)
  __syncthreads();   // drains vmcnt: Bs[0] + af[0] ready

#pragma unroll
  for (int c = 0; c < 4; ++c) {
    const int cb = c & 1;
    if (c < 3) {
      STAGE_B(c + 1, cb ^ 1)
      LOAD_A(c + 1, cb ^ 1)
    }
    bf16x8 ah[2][2], al[2][2];
#pragma unroll
    for (int rf = 0; rf < 2; ++rf)
#pragma unroll
      for (int ktl = 0; ktl < 2; ++ktl)
        split8(af[cb][rf][ktl][0], af[cb][rf][ktl][1], ah[rf][ktl], al[rf][ktl]);
#pragma unroll
    for (int ktl = 0; ktl < 2; ++ktl) {
#pragma unroll
      for (int nf = 0; nf < 8; ++nf) {
        const bf16x8 bh =
            *(const bf16x8*)&Bs[cb][(ktl * 16 + nf * 2) * 512 + lane * 8];
        const bf16x8 bl =
            *(const bf16x8*)&Bs[cb][(ktl * 16 + nf * 2 + 1) * 512 + lane * 8];
#pragma unroll
        for (int rf = 0; rf < 2; ++rf) {
          acc[rf][nf] = __builtin_amdgcn_mfma_f32_16x16x32_bf16(
              ah[rf][ktl], bh, acc[rf][nf], 0, 0, 0);
          acc[rf][nf] = __builtin_amdgcn_mfma_f32_16x16x32_bf16(
              ah[rf][ktl], bl, acc[rf][nf], 0, 0, 0);
          acc[rf][nf] = __builtin_amdgcn_mfma_f32_16x16x32_bf16(
              al[rf][ktl], bh, acc[rf][nf], 0, 0, 0);
        }
      }
    }
    __syncthreads();   // Bs[cb^1] staged; safe to reuse Bs[cb] next iter
  }
#undef STAGE_B
#undef LOAD_A

  // epilogue: C/D frag layout col=lane&15, row=(lane>>4)*4+i  (bf16 out)
#pragma unroll
  for (int rf = 0; rf < 2; ++rf) {
#pragma unroll
    for (int i = 0; i < 4; ++i) {
      const int row = rowW + rf * 16 + ((lane >> 4) << 2) + i;
      if (row < M) {
        unsigned short* op = Wh + (size_t)row * HID + lr;
#pragma unroll
        for (int nf = 0; nf < 8; ++nf) op[nf * 16] = f2bf(acc[rf][nf][i] + bv[nf]);
      }
    }
  }
}

// ---------------------------------------------------------------------------
// per-dst degree counts, both relations batched over blockIdx.y
// ---------------------------------------------------------------------------
__global__ __launch_bounds__(256)
void count_deg2(const int* __restrict__ dstA, const int* __restrict__ dstB,
                int* __restrict__ cntA, int* __restrict__ cntB, int n) {
  const int i = blockIdx.x * 256 + threadIdx.x;
  const int* __restrict__ dst = blockIdx.y ? dstB : dstA;
  int* __restrict__ cnt = blockIdx.y ? cntB : cntA;
  if (i < n) atomicAdd(&cnt[dst[i]], 1);
}

// ---------------------------------------------------------------------------
// bucket counts: bcnt[b] = sum of 16 per-dst counts (batched over y)
// ---------------------------------------------------------------------------
__global__ __launch_bounds__(256)
void bucket_sum(const int* __restrict__ cntBase, int* __restrict__ bcntBase) {
  const int b = blockIdx.x * 256 + threadIdx.x;
  if (b >= NBKT) return;
  const int y = blockIdx.y;
  const int4* p = (const int4*)(cntBase + (size_t)y * N_USER + (size_t)b * 16);
  int s = 0;
#pragma unroll
  for (int q = 0; q < 4; ++q) { const int4 v = p[q]; s += v.x + v.y + v.z + v.w; }
  bcntBase[y * NBKT + b] = s;
}

// ---------------------------------------------------------------------------
// 3-phase multi-block exclusive scan over bucket counts (2 relations via y)
// ---------------------------------------------------------------------------
__global__ __launch_bounds__(256)
void scan_p1(const int* __restrict__ cntBase, int n, int* __restrict__ posBase,
             int* __restrict__ bsumBase) {
  __shared__ int sh[256];
  const int y = blockIdx.y, b = blockIdx.x, t = threadIdx.x;
  const int* cnt = cntBase + (size_t)y * n;
  int* pos = posBase + (size_t)y * n;
  int* bsum = bsumBase + (size_t)y * SCAN_BLK;
  const int i = b * 256 + t;
  const int v = (i < n) ? cnt[i] : 0;
  sh[t] = v;
  __syncthreads();
#pragma unroll
  for (int d = 1; d < 256; d <<= 1) {
    const int x = (t >= d) ? sh[t - d] : 0;
    __syncthreads();
    sh[t] += x;
    __syncthreads();
  }
  if (i < n) pos[i] = sh[t] - v;
  if (t == 255) bsum[b] = sh[255];
}

__global__ __launch_bounds__(64)
void scan_p2(int* __restrict__ bsumBase, int nblk) {
  __shared__ int sh[64];
  int* bsum = bsumBase + (size_t)blockIdx.x * SCAN_BLK;
  const int t = threadIdx.x;
  const int v = (t < nblk) ? bsum[t] : 0;
  sh[t] = v;
  __syncthreads();
#pragma unroll
  for (int d = 1; d < 64; d <<= 1) {
    const int x = (t >= d) ? sh[t - d] : 0;
    __syncthreads();
    sh[t] += x;
    __syncthreads();
  }
  if (t < nblk) bsum[t] = sh[t] - v;
}

__global__ __launch_bounds__(256)
void scan_p3(int* __restrict__ posBase, const int* __restrict__ bsumBase, int n) {
  const int y = blockIdx.y;
  int* pos = posBase + (size_t)y * n;
  const int* bsum = bsumBase + (size_t)y * SCAN_BLK;
  const int i = blockIdx.x * 256 + threadIdx.x;
  if (i < n) pos[i] += bsum[blockIdx.x];
}

// ---------------------------------------------------------------------------
// bin edges into 16-dst buckets. Record = src | (dst&15)<<27.
// ---------------------------------------------------------------------------
__global__ __launch_bounds__(256)
void bin_edges(const int* __restrict__ srcA, const int* __restrict__ dstA,
               const int* __restrict__ srcB, const int* __restrict__ dstB,
               int* __restrict__ boff, uint32_t* __restrict__ ebuf, int n) {
  const int e = blockIdx.x * 256 + threadIdx.x;
  if (e >= n) return;
  const int y = blockIdx.y;
  const int* __restrict__ src = y ? srcB : srcA;
  const int* __restrict__ dst = y ? dstB : dstA;
  const int d = dst[e];
  const int p = atomicAdd(&boff[y * NBKT + (d >> 4)], 1);
  ebuf[(size_t)y * N_EDGE + p] = (uint32_t)src[e] | ((uint32_t)(d & 15) << 27);
}

// ---------------------------------------------------------------------------
// in-place intra-bucket counting sort by dlow; emits per-dst row starts.
// ---------------------------------------------------------------------------
__global__ __launch_bounds__(256)
void bucket_sort(const int* __restrict__ cnt, const int* __restrict__ bcnt,
                 const int* __restrict__ boff, uint32_t* __restrict__ ebufBase,
                 int* __restrict__ pos) {
  __shared__ int scnt[16], pref[16], cur[16];
  const int y = blockIdx.y, b = blockIdx.x, t = threadIdx.x;
  const int end = boff[y * NBKT + b];
  const int ne  = bcnt[y * NBKT + b];
  const int beg = end - ne;
  uint32_t* eb = ebufBase + (size_t)y * N_EDGE;
  if (t < 16) scnt[t] = cnt[(size_t)y * N_USER + b * 16 + t];
  __syncthreads();
  if (t < 16) {
    int p = 0;
    for (int j = 0; j < t; ++j) p += scnt[j];
    pref[t] = p;
    cur[t]  = 0;
    pos[(size_t)y * N_USER + b * 16 + t] = beg + p;
  }
  __syncthreads();
  uint32_t myrec[8];
  int nm = 0;
  for (int i = t; i < ne; i += 256) {
    if (nm < 8) myrec[nm] = eb[beg + i];
    ++nm;
  }
  __syncthreads();
#pragma unroll
  for (int q = 0; q < 8; ++q) {
    if (q < nm) {
      const uint32_t rec = myrec[q];
      const int dlow = (int)(rec >> 27);
      const int slot = atomicAdd(&cur[dlow], 1);
      eb[beg + pref[dlow] + slot] = rec;
    }
  }
}

// ---------------------------------------------------------------------------
// Wfuse[128,16] = W1 @ Wout ; bfuse[16] = b1 @ Wout + bout. One block.
// ---------------------------------------------------------------------------
__global__ __launch_bounds__(256)
void make_wfuse(const float* __restrict__ W1, const float* __restrict__ b1,
                const float* __restrict__ Wout, const float* __restrict__ bout,
                float* __restrict__ Wf, float* __restrict__ bf) {
  __shared__ float Ws[HID * OUT_DIM];
  const int t = threadIdx.x;
  {
    const float4* s0 = (const float4*)Wout;
    float4* dp = (float4*)Ws;
    dp[t]       = s0[t];
    dp[t + 256] = s0[t + 256];
  }
  __syncthreads();
  const int k  = t >> 1;
  const int j0 = (t & 1) * 8;
  const float* w1row = W1 + (size_t)k * HID;
  float acc[8] = {0.f, 0.f, 0.f, 0.f, 0.f, 0.f, 0.f, 0.f};
  for (int m = 0; m < HID; ++m) {
    const float a = w1row[m];
    const float* wr = &Ws[m * OUT_DIM + j0];
#pragma unroll
    for (int q = 0; q < 8; ++q) acc[q] += a * wr[q];
  }
#pragma unroll
  for (int q = 0; q < 8; ++q) Wf[(size_t)k * OUT_DIM + j0 + q] = acc[q];
  if (t < OUT_DIM) {
    float s = bout[t];
    for (int m = 0; m < HID; ++m) s += b1[m] * Ws[m * OUT_DIM + t];
    bf[t] = s;
  }
}

// ---------------------------------------------------------------------------
// gather-1: h[d,128](fp32) = leaky(mean over edges of bf16 wh rows).
// 16 lanes per dst row (uint4 = 8 bf16 each), 16 rows per block, 4-way unroll.
// ---------------------------------------------------------------------------
static __device__ __forceinline__ void acc_bf8(float* a, uint4 u) {
  a[0] += __uint_as_float(u.x << 16);
  a[1] += __uint_as_float(u.x & 0xffff0000u);
  a[2] += __uint_as_float(u.y << 16);
  a[3] += __uint_as_float(u.y & 0xffff0000u);
  a[4] += __uint_as_float(u.z << 16);
  a[5] += __uint_as_float(u.z & 0xffff0000u);
  a[6] += __uint_as_float(u.w << 16);
  a[7] += __uint_as_float(u.w & 0xffff0000u);
}

__global__ __launch_bounds__(256)
void gather_mean_bf16(const unsigned short* __restrict__ bh,
                      const int* __restrict__ pos, const int* __restrict__ cnt,
                      const uint32_t* __restrict__ ebuf, float* __restrict__ out) {
  const int row = blockIdx.x * 16 + (threadIdx.x >> 4);
  const int c = threadIdx.x & 15;
  const int beg = pos[row];
  const int cn  = cnt[row];
  float acc[8] = {0.f, 0.f, 0.f, 0.f, 0.f, 0.f, 0.f, 0.f};
  int i = 0;
  for (; i + 4 <= cn; i += 4) {
    const int s0 = (int)(ebuf[beg + i]     & SRC_MASK);
    const int s1 = (int)(ebuf[beg + i + 1] & SRC_MASK);
    const int s2 = (int)(ebuf[beg + i + 2] & SRC_MASK);
    const int s3 = (int)(ebuf[beg + i + 3] & SRC_MASK);
    const uint4 v0 = *((const uint4*)(bh + (size_t)s0 * HID) + c);
    const uint4 v1 = *((const uint4*)(bh + (size_t)s1 * HID) + c);
    const uint4 v2 = *((const uint4*)(bh + (size_t)s2 * HID) + c);
    const uint4 v3 = *((const uint4*)(bh + (size_t)s3 * HID) + c);
    acc_bf8(acc, v0); acc_bf8(acc, v1); acc_bf8(acc, v2); acc_bf8(acc, v3);
  }
  for (; i < cn; ++i) {
    const int s = (int)(ebuf[beg + i] & SRC_MASK);
    const uint4 v = *((const uint4*)(bh + (size_t)s * HID) + c);
    acc_bf8(acc, v);
  }
  const float inv = cn > 0 ? 1.0f / (float)cn : 0.0f;
  float4 o0, o1;
  float r[8];
#pragma unroll
  for (int q = 0; q < 8; ++q) {
    float v = acc[q] * inv;
    r[q] = v > 0.f ? v : LEAKY_SLOPE * v;
  }
  o0 = make_float4(r[0], r[1], r[2], r[3]);
  o1 = make_float4(r[4], r[5], r[6], r[7]);
  float* op = out + (size_t)row * HID + c * 8;
  *(float4*)op = o0;
  *(float4*)(op + 4) = o1;
}

// ---------------------------------------------------------------------------
// z[M,16] = H[M,128] @ Wf[128,16]   (no bias)
// ---------------------------------------------------------------------------
__global__ __launch_bounds__(256)
void gemm_z16(const float* __restrict__ H, const float* __restrict__ Wf,
              float* __restrict__ z, int M) {
  __shared__ float Ws[HID * OUT_DIM];
  __shared__ float Hs[16 * HID];
  const int t = threadIdx.x;
  const int row0 = blockIdx.x * 16;
  {
    const float4* s0 = (const float4*)Wf;
    float4* dp = (float4*)Ws;
    dp[t]       = s0[t];
    dp[t + 256] = s0[t + 256];
    const float4* s1 = (const float4*)(H + (size_t)row0 * HID);
    float4* hp = (float4*)Hs;
    hp[t]       = s1[t];
    hp[t + 256] = s1[t + 256];
  }
  __syncthreads();
  const int r = t >> 4, c = t & 15;
  float s = 0.f;
  const float* h = &Hs[r * HID];
#pragma unroll 8
  for (int k = 0; k < HID; ++k) s += h[k] * Ws[k * OUT_DIM + c];
  z[(size_t)(row0 + r) * OUT_DIM + c] = s;
}

// ---------------------------------------------------------------------------
// gather-2: out[d,16] = mean(z[src]) + (cn>0 ? bfuse : bout)
// 16 lanes per dst row (one float each), 16 rows per block, 4-way unroll.
// ---------------------------------------------------------------------------
__global__ __launch_bounds__(256)
void gather_mean16(const float* __restrict__ z, const int* __restrict__ pos,
                   const int* __restrict__ cnt, const uint32_t* __restrict__ ebuf,
                   const float* __restrict__ bfuse, const float* __restrict__ bout,
                   float* __restrict__ out) {
  const int row = blockIdx.x * 16 + (threadIdx.x >> 4);
  const int c = threadIdx.x & 15;
  const int beg = pos[row];
  const int cn  = cnt[row];
  float acc = 0.f;
  int i = 0;
  for (; i + 4 <= cn; i += 4) {
    const int s0 = (int)(ebuf[beg + i]     & SRC_MASK);
    const int s1 = (int)(ebuf[beg + i + 1] & SRC_MASK);
    const int s2 = (int)(ebuf[beg + i + 2] & SRC_MASK);
    const int s3 = (int)(ebuf[beg + i + 3] & SRC_MASK);
    const float v0 = z[(size_t)s0 * OUT_DIM + c];
    const float v1 = z[(size_t)s1 * OUT_DIM + c];
    const float v2 = z[(size_t)s2 * OUT_DIM + c];
    const float v3 = z[(size_t)s3 * OUT_DIM + c];
    acc += v0 + v1 + v2 + v3;
  }
  for (; i < cn; ++i) {
    const int s = (int)(ebuf[beg + i] & SRC_MASK);
    acc += z[(size_t)s * OUT_DIM + c];
  }
  float o;
  if (cn > 0) o = acc * (1.0f / (float)cn) + bfuse[c];
  else        o = bout[c];
  out[(size_t)row * OUT_DIM + c] = o;
}

// ---------------------------------------------------------------------------
extern "C" void kernel_launch(void* const* d_in, const int* in_sizes, int n_in,
                              void* d_out, int out_size, void* d_ws, size_t ws_size,
                              hipStream_t stream) {
  const float* feat_user  = (const float*)d_in[0];
  // d_in[1] feat_item : dead (never reaches the output)
  const int*   src_clicks = (const int*)d_in[2];
  const int*   dst_clicks = (const int*)d_in[3];
  const int*   src_cb     = (const int*)d_in[4];
  const int*   dst_cb     = (const int*)d_in[5];
  const float* Win_user   = (const float*)d_in[6];
  const float* bin_user   = (const float*)d_in[7];
  // d_in[8..9] Win_item/bin_item : dead
  const float* W0_clicks  = (const float*)d_in[10];
  const float* b0_clicks  = (const float*)d_in[11];
  // d_in[12..15] W0_cb/b0_cb/W1_clicks/b1_clicks : dead
  const float* W1_cb      = (const float*)d_in[16];
  const float* b1_cb      = (const float*)d_in[17];
  const float* Wout       = (const float*)d_in[18];
  const float* bout       = (const float*)d_in[19];
  float* out = (float*)d_out;

  const size_t SZ  = (size_t)N_USER * HID * sizeof(float);           // 51.2 MB
  const size_t SZH = (size_t)N_USER * HID * sizeof(unsigned short);  // 25.6 MB
  const size_t SZZ = (size_t)N_USER * OUT_DIM * sizeof(float);       // 6.4 MB
  char* ws = (char*)d_ws;
  float* buf0          = (float*)ws;                   // h_i0
  unsigned short* bh   = (unsigned short*)(ws + SZ);   // wh_u0 (bf16)
  float* z0            = (float*)(ws + SZ + SZH);      // h_i0 @ Wfuse
  // Bswz/bf0 overlap the z0 region: they are dead before gemm_z16 writes z0.
  unsigned short* Bswz = (unsigned short*)z0;                  // [64K] = 128 KB
  float* bf0v          = (float*)((char*)z0 + 131072);         // [128]
  float* Wf            = (float*)(ws + SZ + SZH + SZZ);        // [128,16]
  float* bf            = Wf + HID * OUT_DIM;                   // [16]
  int* cnt  = (int*)(bf + OUT_DIM);               // [2][100000] per-dst degree
  int* pos  = cnt + 2 * N_USER;                   // [2][100000] per-dst row beg
  int* bcnt = pos + 2 * N_USER;                   // [2][NBKT]
  int* boff = bcnt + 2 * NBKT;                    // [2][NBKT]
  int* bsum = boff + 2 * NBKT;                    // [2][SCAN_BLK]
  uint32_t* ebuf = (uint32_t*)(bsum + 2 * SCAN_BLK + 14);  // [2][N_EDGE]

  const int G16 = N_USER / 16;                    // 6250
  const int GE  = (N_EDGE + 255) / 256;           // 3907
  const int GM  = (N_USER + 127) / 128;           // 782

  // --- bucketed dst-sorted edge list for both relations ---
  hipMemsetAsync(cnt, 0, (size_t)2 * N_USER * sizeof(int), stream);
  count_deg2<<<dim3(GE, 2), 256, 0, stream>>>(dst_clicks, dst_cb, cnt, cnt + N_USER, N_EDGE);
  bucket_sum<<<dim3(SCAN_BLK, 2), 256, 0, stream>>>(cnt, bcnt);
  scan_p1<<<dim3(SCAN_BLK, 2), 256, 0, stream>>>(bcnt, NBKT, boff, bsum);
  scan_p2<<<2, 64, 0, stream>>>(bsum, SCAN_BLK);
  scan_p3<<<dim3(SCAN_BLK, 2), 256, 0, stream>>>(boff, bsum, NBKT);
  bin_edges<<<dim3(GE, 2), 256, 0, stream>>>(src_clicks, dst_clicks, src_cb, dst_cb,
                                             boff, ebuf, N_EDGE);
  bucket_sort<<<dim3(NBKT, 2), 256, 0, stream>>>(cnt, bcnt, boff, ebuf, pos);

  // fused final projection: Wf = W1_cb @ Wout, bf = b1_cb @ Wout + bout
  make_wfuse<<<1, 256, 0, stream>>>(W1_cb, b1_cb, Wout, bout, Wf, bf);
  // fused input projection: Bswz = split/swizzled(Win_user @ W0_clicks),
  // bf0 = bin_user @ W0_clicks + b0_clicks
  make_wfuse0<<<128, 256, 0, stream>>>(Win_user, bin_user, W0_clicks, b0_clicks,
                                       Bswz, bf0v);

  // 1) wh_u0 = feat_user @ (Win@W0) + bf0  (split-bf16 MFMA) -> bh (bf16)
  gemm_feat_mfma<<<GM, 256, 0, stream>>>(feat_user, Bswz, bf0v, bh, N_USER);
  // 2) h_i0 = leaky(seg_mean over clicks)                    -> buf0 (fp32)
  gather_mean_bf16<<<G16, 256, 0, stream>>>(bh, pos, cnt, ebuf, buf0);
  // 3) z0 = h_i0 @ (W1_cb @ Wout)                            -> z0
  gemm_z16<<<G16, 256, 0, stream>>>(buf0, Wf, z0, N_ITEM);
  // 4) out = seg_mean(z0 over clicked_by) + bias select      -> out
  gather_mean16<<<G16, 256, 0, stream>>>(z0, pos + N_USER, cnt + N_USER,
                                         ebuf + N_EDGE, bf, bout, out);
}

// Round 2
// 408.231 us; speedup vs baseline: 1.5443x; 1.3605x over previous
//
#include <hip/hip_runtime.h>
#include <hip/hip_bf16.h>
#include <cstddef>
#include <cstdint>

#define N_USER 100000
#define N_ITEM 100000
#define N_EDGE 1000000
#define IN_DIM 256
#define HID 128
#define OUT_DIM 16
#define LEAKY_SLOPE 0.01f
#define SRC_MASK 0x07FFFFFFu

// edge partition parameters
#define NC 98            // coarse buckets: dst>>10, 100000/1024 -> 0..97
#define CAPB 12288       // padded records per bucket (E[n]=10240, 20 sigma)
#define TILE 4096        // edges per part_coarse block (16/thread)

typedef __attribute__((ext_vector_type(8))) short bf16x8;
typedef __attribute__((ext_vector_type(4))) float f32x4;

static __device__ __forceinline__ unsigned short f2bf(float f) {
  // RTNE bf16 (matches __float2bfloat16 for normal values)
  unsigned int u = __float_as_uint(f);
  u = (u + 0x7FFFu + ((u >> 16) & 1u)) >> 16;
  return (unsigned short)u;
}

// ---------------------------------------------------------------------------
// split fp32 -> (hi, lo) bf16: a ~= hi + lo with ~16-bit effective mantissa.
// ---------------------------------------------------------------------------
static __device__ __forceinline__ void split8(const float4 x, const float4 y,
                                              bf16x8& hi, bf16x8& lo) {
  const float f[8] = {x.x, x.y, x.z, x.w, y.x, y.y, y.z, y.w};
#pragma unroll
  for (int j = 0; j < 8; ++j) {
    const unsigned u = __float_as_uint(f[j]);
    hi[j] = (short)(u >> 16);
    const float lf = f[j] - __uint_as_float(u & 0xffff0000u);
    lo[j] = (short)(__float_as_uint(lf) >> 16);
  }
}

// ---------------------------------------------------------------------------
// Pass A: coarse partition of edges into NC padded bucket regions.
// Per block: LDS histogram -> LDS counting sort of the tile -> one global
// atomicAdd per touched bucket -> fully coalesced region writes.
// Record = src | (dst&1023)<<17.
// ---------------------------------------------------------------------------
__global__ __launch_bounds__(256)
void part_coarse(const int* __restrict__ srcA, const int* __restrict__ dstA,
                 const int* __restrict__ srcB, const int* __restrict__ dstB,
                 int* __restrict__ gcur, uint32_t* __restrict__ tmp, int n) {
  __shared__ uint32_t srec[TILE];       // 16 KB tile-sorted records
  __shared__ unsigned char sbkt[TILE];  // 4 KB bucket id per staged record
  __shared__ int hist[NC], lofs[NC], gbase[NC], lcur[NC];
  const int y = blockIdx.y, t = threadIdx.x;
  const int* __restrict__ src = y ? srcB : srcA;
  const int* __restrict__ dst = y ? dstB : dstA;
  const int e0 = blockIdx.x * TILE;
  const int ne = min(TILE, n - e0);

  for (int i = t; i < NC; i += 256) hist[i] = 0;
  __syncthreads();

  uint32_t rec[16];
  int bk[16];
#pragma unroll
  for (int q = 0; q < 16; ++q) {
    const int i = t + q * 256;
    if (i < ne) {
      const int d = dst[e0 + i];
      rec[q] = (uint32_t)src[e0 + i] | ((uint32_t)(d & 1023) << 17);
      bk[q] = d >> 10;
      atomicAdd(&hist[bk[q]], 1);
    } else {
      bk[q] = -1;
    }
  }
  __syncthreads();

  if (t == 0) {
    int run = 0;
#pragma unroll 1
    for (int i = 0; i < NC; ++i) { lofs[i] = run; run += hist[i]; }
  }
  __syncthreads();
  if (t < NC) {
    lcur[t] = 0;
    gbase[t] = atomicAdd(&gcur[y * NC + t], hist[t]);
  }
  __syncthreads();

#pragma unroll
  for (int q = 0; q < 16; ++q) {
    if (bk[q] >= 0) {
      const int p = lofs[bk[q]] + atomicAdd(&lcur[bk[q]], 1);
      srec[p] = rec[q];
      sbkt[p] = (unsigned char)bk[q];
    }
  }
  __syncthreads();

  uint32_t* __restrict__ outp = tmp + (size_t)y * NC * CAPB;
  for (int i = t; i < ne; i += 256) {
    const int b = sbkt[i];
    outp[(size_t)b * CAPB + gbase[b] + (i - lofs[b])] = srec[i];
  }
}

// ---------------------------------------------------------------------------
// Pass B: per (bucket, relation) block. LDS per-dst histogram over the 1024
// dst rows of the bucket + block scan -> emits cnt[] and pos[] (relation-
// relative, padded layout) -> in-L2 scatter of records to final dst order.
// Final ebuf record = src only.
// ---------------------------------------------------------------------------
__global__ __launch_bounds__(256)
void part_fine(const uint32_t* __restrict__ tmp, const int* __restrict__ gcur,
               uint32_t* __restrict__ ebuf, int* __restrict__ pos,
               int* __restrict__ cnt) {
  __shared__ int dcnt[1024];
  __shared__ int sh[256];
  const int y = blockIdx.y, b = blockIdx.x, t = threadIdx.x;
  const int ne = gcur[y * NC + b];
  const uint32_t* __restrict__ in = tmp + ((size_t)y * NC + b) * CAPB;

  for (int i = t; i < 1024; i += 256) dcnt[i] = 0;
  __syncthreads();
  for (int i = t; i < ne; i += 256) atomicAdd(&dcnt[in[i] >> 17], 1);
  __syncthreads();

  const int bi = t * 4;
  const int v0 = dcnt[bi], v1 = dcnt[bi + 1], v2 = dcnt[bi + 2], v3 = dcnt[bi + 3];
  const int tsum = v0 + v1 + v2 + v3;
  sh[t] = tsum;
  __syncthreads();
#pragma unroll
  for (int d = 1; d < 256; d <<= 1) {
    const int x = (t >= d) ? sh[t - d] : 0;
    __syncthreads();
    sh[t] += x;
    __syncthreads();
  }
  const int p0 = sh[t] - tsum;
  const int p1 = p0 + v0, p2 = p1 + v1, p3 = p2 + v2;
  dcnt[bi] = p0; dcnt[bi + 1] = p1; dcnt[bi + 2] = p2; dcnt[bi + 3] = p3;

  const int drow0 = (b << 10) + bi;
  const int prel = b * CAPB;
  int* __restrict__ cw = cnt + (size_t)y * N_USER;
  int* __restrict__ pw = pos + (size_t)y * N_USER;
  if (drow0 + 0 < N_USER) { cw[drow0 + 0] = v0; pw[drow0 + 0] = prel + p0; }
  if (drow0 + 1 < N_USER) { cw[drow0 + 1] = v1; pw[drow0 + 1] = prel + p1; }
  if (drow0 + 2 < N_USER) { cw[drow0 + 2] = v2; pw[drow0 + 2] = prel + p2; }
  if (drow0 + 3 < N_USER) { cw[drow0 + 3] = v3; pw[drow0 + 3] = prel + p3; }
  __syncthreads();

  uint32_t* __restrict__ outp = ebuf + ((size_t)y * NC + b) * CAPB;
  for (int i = t; i < ne; i += 256) {
    const uint32_t r = in[i];
    const int p = atomicAdd(&dcnt[r >> 17], 1);
    outp[p] = r & 0x1FFFFu;
  }
}

// ---------------------------------------------------------------------------
// Build fused layer-0 weight Wf0 = Win_user @ W0_clicks [256,128], pre-SPLIT
// into (hi,lo) bf16 and pre-SWIZZLED into MFMA B-fragment order, plus
// bf0 = bin_user @ W0_clicks + b0_clicks.
// ---------------------------------------------------------------------------
__global__ __launch_bounds__(256)
void make_wfuse0(const float* __restrict__ Win, const float* __restrict__ bin,
                 const float* __restrict__ W0, const float* __restrict__ b0,
                 unsigned short* __restrict__ Bswz, float* __restrict__ bf0) {
  const int t = threadIdx.x;
  const int r = blockIdx.x * 2 + (t >> 7);   // k index in [0,256)
  const int n = t & 127;                     // col in [0,128)
  const float* wr = Win + (size_t)r * HID;
  float s = 0.f;
#pragma unroll 8
  for (int m = 0; m < HID; ++m) s += wr[m] * W0[(size_t)m * HID + n];
  const unsigned u = __float_as_uint(s);
  const unsigned short hi = (unsigned short)(u >> 16);
  const float lf = s - __uint_as_float(u & 0xffff0000u);
  const unsigned short lo = (unsigned short)(__float_as_uint(lf) >> 16);
  const int kt = r >> 5, lh = (r >> 3) & 3, j = r & 7;
  const int nf = n >> 4, lane = lh * 16 + (n & 15);
  Bswz[(size_t)(kt * 16 + nf * 2) * 512 + lane * 8 + j] = hi;
  Bswz[(size_t)(kt * 16 + nf * 2 + 1) * 512 + lane * 8 + j] = lo;
  if (blockIdx.x == 0 && t < HID) {
    float s2 = b0[t];
    for (int m = 0; m < HID; ++m) s2 += bin[m] * W0[(size_t)m * HID + t];
    bf0[t] = s2;
  }
}

// ---------------------------------------------------------------------------
// Wh[M,128](bf16) = A[M,256](fp32) @ Wf0 + bf0 via split-bf16 MFMA.
// ---------------------------------------------------------------------------
__global__ __launch_bounds__(256, 2)
void gemm_feat_mfma(const float* __restrict__ A,
                    const unsigned short* __restrict__ Bswz,
                    const float* __restrict__ bias,
                    unsigned short* __restrict__ Wh, int M) {
  __shared__ unsigned short Bs[2][16384];   // 2 x 32 KB
  const int t = threadIdx.x;
  const int w = t >> 6, lane = t & 63;
  const int rowW = blockIdx.x * 128 + w * 32;
  const int lr = lane & 15;                 // row-in-frag / col-in-frag
  const int lk = (lane >> 4) << 3;          // k offset 0/8/16/24

  int r0 = rowW + lr;      if (r0 >= M) r0 = M - 1;
  int r1 = rowW + 16 + lr; if (r1 >= M) r1 = M - 1;
  const float* pa0 = A + (size_t)r0 * IN_DIM + lk;
  const float* pa1 = A + (size_t)r1 * IN_DIM + lk;

  float bv[8];
#pragma unroll
  for (int nf = 0; nf < 8; ++nf) bv[nf] = bias[nf * 16 + lr];

  f32x4 acc[2][8];
#pragma unroll
  for (int rf = 0; rf < 2; ++rf)
#pragma unroll
    for (int nf = 0; nf < 8; ++nf)
#pragma unroll
      for (int q = 0; q < 4; ++q) acc[rf][nf][q] = 0.f;

  float4 af[2][2][2][2];  // [buf][rf][ktl][half]

#define STAGE_B(c, buf)                                                        \
  {                                                                            \
    _Pragma("unroll")                                                          \
    for (int i = 0; i < 8; ++i)                                                \
      __builtin_amdgcn_global_load_lds(                                        \
          (const __attribute__((address_space(1))) unsigned int*)              \
              ((const char*)Bswz + (c) * 32768 + i * 4096 + t * 16),           \
          (__attribute__((address_space(3))) unsigned int*)                    \
              &Bs[buf][i * 2048 + w * 512],                                    \
          16, 0, 0);                                                           \
  }

#define LOAD_A(c, buf)                                                         \
  {                                                                            \
    _Pragma("unroll")                                                          \
    for (int ktl = 0; ktl < 2; ++ktl) {                                        \
      af[buf][0][ktl][0] = *(const float4*)(pa0 + (c) * 64 + ktl * 32);        \
      af[buf][0][ktl][1] = *(const float4*)(pa0 + (c) * 64 + ktl * 32 + 4);    \
      af[buf][1][ktl][0] = *(const float4*)(pa1 + (c) * 64 + ktl * 32);        \
      af[buf][1][ktl][1] = *(const float4*)(pa1 + (c) * 64 + ktl * 32 + 4);    \
    }                                                                          \
  }

  STAGE_B(0, 0)
  LOAD_A(0, 0)
  __syncthreads();   // drains vmcnt: Bs[0] + af[0] ready

#pragma unroll
  for (int c = 0; c < 4; ++c) {
    const int cb = c & 1;
    if (c < 3) {
      STAGE_B(c + 1, cb ^ 1)
      LOAD_A(c + 1, cb ^ 1)
    }
    bf16x8 ah[2][2], al[2][2];
#pragma unroll
    for (int rf = 0; rf < 2; ++rf)
#pragma unroll
      for (int ktl = 0; ktl < 2; ++ktl)
        split8(af[cb][rf][ktl][0], af[cb][rf][ktl][1], ah[rf][ktl], al[rf][ktl]);
#pragma unroll
    for (int ktl = 0; ktl < 2; ++ktl) {
#pragma unroll
      for (int nf = 0; nf < 8; ++nf) {
        const bf16x8 bh =
            *(const bf16x8*)&Bs[cb][(ktl * 16 + nf * 2) * 512 + lane * 8];
        const bf16x8 bl =
            *(const bf16x8*)&Bs[cb][(ktl * 16 + nf * 2 + 1) * 512 + lane * 8];
#pragma unroll
        for (int rf = 0; rf < 2; ++rf) {
          acc[rf][nf] = __builtin_amdgcn_mfma_f32_16x16x32_bf16(
              ah[rf][ktl], bh, acc[rf][nf], 0, 0, 0);
          acc[rf][nf] = __builtin_amdgcn_mfma_f32_16x16x32_bf16(
              ah[rf][ktl], bl, acc[rf][nf], 0, 0, 0);
          acc[rf][nf] = __builtin_amdgcn_mfma_f32_16x16x32_bf16(
              al[rf][ktl], bh, acc[rf][nf], 0, 0, 0);
        }
      }
    }
    __syncthreads();   // Bs[cb^1] staged; safe to reuse Bs[cb] next iter
  }
#undef STAGE_B
#undef LOAD_A

  // epilogue: C/D frag layout col=lane&15, row=(lane>>4)*4+i  (bf16 out)
#pragma unroll
  for (int rf = 0; rf < 2; ++rf) {
#pragma unroll
    for (int i = 0; i < 4; ++i) {
      const int row = rowW + rf * 16 + ((lane >> 4) << 2) + i;
      if (row < M) {
        unsigned short* op = Wh + (size_t)row * HID + lr;
#pragma unroll
        for (int nf = 0; nf < 8; ++nf) op[nf * 16] = f2bf(acc[rf][nf][i] + bv[nf]);
      }
    }
  }
}

// ---------------------------------------------------------------------------
// Wfuse[128,16] = W1 @ Wout ; bfuse[16] = b1 @ Wout + bout. One block.
// ---------------------------------------------------------------------------
__global__ __launch_bounds__(256)
void make_wfuse(const float* __restrict__ W1, const float* __restrict__ b1,
                const float* __restrict__ Wout, const float* __restrict__ bout,
                float* __restrict__ Wf, float* __restrict__ bf) {
  __shared__ float Ws[HID * OUT_DIM];
  const int t = threadIdx.x;
  {
    const float4* s0 = (const float4*)Wout;
    float4* dp = (float4*)Ws;
    dp[t]       = s0[t];
    dp[t + 256] = s0[t + 256];
  }
  __syncthreads();
  const int k  = t >> 1;
  const int j0 = (t & 1) * 8;
  const float* w1row = W1 + (size_t)k * HID;
  float acc[8] = {0.f, 0.f, 0.f, 0.f, 0.f, 0.f, 0.f, 0.f};
  for (int m = 0; m < HID; ++m) {
    const float a = w1row[m];
    const float* wr = &Ws[m * OUT_DIM + j0];
#pragma unroll
    for (int q = 0; q < 8; ++q) acc[q] += a * wr[q];
  }
#pragma unroll
  for (int q = 0; q < 8; ++q) Wf[(size_t)k * OUT_DIM + j0 + q] = acc[q];
  if (t < OUT_DIM) {
    float s = bout[t];
    for (int m = 0; m < HID; ++m) s += b1[m] * Ws[m * OUT_DIM + t];
    bf[t] = s;
  }
}

// ---------------------------------------------------------------------------
// gather-1: h[d,128](fp32) = leaky(mean over edges of bf16 wh rows).
// ---------------------------------------------------------------------------
static __device__ __forceinline__ void acc_bf8(float* a, uint4 u) {
  a[0] += __uint_as_float(u.x << 16);
  a[1] += __uint_as_float(u.x & 0xffff0000u);
  a[2] += __uint_as_float(u.y << 16);
  a[3] += __uint_as_float(u.y & 0xffff0000u);
  a[4] += __uint_as_float(u.z << 16);
  a[5] += __uint_as_float(u.z & 0xffff0000u);
  a[6] += __uint_as_float(u.w << 16);
  a[7] += __uint_as_float(u.w & 0xffff0000u);
}

__global__ __launch_bounds__(256)
void gather_mean_bf16(const unsigned short* __restrict__ bh,
                      const int* __restrict__ pos, const int* __restrict__ cnt,
                      const uint32_t* __restrict__ ebuf, float* __restrict__ out) {
  const int row = blockIdx.x * 16 + (threadIdx.x >> 4);
  const int c = threadIdx.x & 15;
  const int beg = pos[row];
  const int cn  = cnt[row];
  float acc[8] = {0.f, 0.f, 0.f, 0.f, 0.f, 0.f, 0.f, 0.f};
  int i = 0;
  for (; i + 4 <= cn; i += 4) {
    const int s0 = (int)(ebuf[beg + i]     & SRC_MASK);
    const int s1 = (int)(ebuf[beg + i + 1] & SRC_MASK);
    const int s2 = (int)(ebuf[beg + i + 2] & SRC_MASK);
    const int s3 = (int)(ebuf[beg + i + 3] & SRC_MASK);
    const uint4 v0 = *((const uint4*)(bh + (size_t)s0 * HID) + c);
    const uint4 v1 = *((const uint4*)(bh + (size_t)s1 * HID) + c);
    const uint4 v2 = *((const uint4*)(bh + (size_t)s2 * HID) + c);
    const uint4 v3 = *((const uint4*)(bh + (size_t)s3 * HID) + c);
    acc_bf8(acc, v0); acc_bf8(acc, v1); acc_bf8(acc, v2); acc_bf8(acc, v3);
  }
  for (; i < cn; ++i) {
    const int s = (int)(ebuf[beg + i] & SRC_MASK);
    const uint4 v = *((const uint4*)(bh + (size_t)s * HID) + c);
    acc_bf8(acc, v);
  }
  const float inv = cn > 0 ? 1.0f / (float)cn : 0.0f;
  float4 o0, o1;
  float r[8];
#pragma unroll
  for (int q = 0; q < 8; ++q) {
    float v = acc[q] * inv;
    r[q] = v > 0.f ? v : LEAKY_SLOPE * v;
  }
  o0 = make_float4(r[0], r[1], r[2], r[3]);
  o1 = make_float4(r[4], r[5], r[6], r[7]);
  float* op = out + (size_t)row * HID + c * 8;
  *(float4*)op = o0;
  *(float4*)(op + 4) = o1;
}

// ---------------------------------------------------------------------------
// z[M,16] = H[M,128] @ Wf[128,16]   (no bias)
// ---------------------------------------------------------------------------
__global__ __launch_bounds__(256)
void gemm_z16(const float* __restrict__ H, const float* __restrict__ Wf,
              float* __restrict__ z, int M) {
  __shared__ float Ws[HID * OUT_DIM];
  __shared__ float Hs[16 * HID];
  const int t = threadIdx.x;
  const int row0 = blockIdx.x * 16;
  {
    const float4* s0 = (const float4*)Wf;
    float4* dp = (float4*)Ws;
    dp[t]       = s0[t];
    dp[t + 256] = s0[t + 256];
    const float4* s1 = (const float4*)(H + (size_t)row0 * HID);
    float4* hp = (float4*)Hs;
    hp[t]       = s1[t];
    hp[t + 256] = s1[t + 256];
  }
  __syncthreads();
  const int r = t >> 4, c = t & 15;
  float s = 0.f;
  const float* h = &Hs[r * HID];
#pragma unroll 8
  for (int k = 0; k < HID; ++k) s += h[k] * Ws[k * OUT_DIM + c];
  z[(size_t)(row0 + r) * OUT_DIM + c] = s;
}

// ---------------------------------------------------------------------------
// gather-2: out[d,16] = mean(z[src]) + (cn>0 ? bfuse : bout)
// ---------------------------------------------------------------------------
__global__ __launch_bounds__(256)
void gather_mean16(const float* __restrict__ z, const int* __restrict__ pos,
                   const int* __restrict__ cnt, const uint32_t* __restrict__ ebuf,
                   const float* __restrict__ bfuse, const float* __restrict__ bout,
                   float* __restrict__ out) {
  const int row = blockIdx.x * 16 + (threadIdx.x >> 4);
  const int c = threadIdx.x & 15;
  const int beg = pos[row];
  const int cn  = cnt[row];
  float acc = 0.f;
  int i = 0;
  for (; i + 4 <= cn; i += 4) {
    const int s0 = (int)(ebuf[beg + i]     & SRC_MASK);
    const int s1 = (int)(ebuf[beg + i + 1] & SRC_MASK);
    const int s2 = (int)(ebuf[beg + i + 2] & SRC_MASK);
    const int s3 = (int)(ebuf[beg + i + 3] & SRC_MASK);
    const float v0 = z[(size_t)s0 * OUT_DIM + c];
    const float v1 = z[(size_t)s1 * OUT_DIM + c];
    const float v2 = z[(size_t)s2 * OUT_DIM + c];
    const float v3 = z[(size_t)s3 * OUT_DIM + c];
    acc += v0 + v1 + v2 + v3;
  }
  for (; i < cn; ++i) {
    const int s = (int)(ebuf[beg + i] & SRC_MASK);
    acc += z[(size_t)s * OUT_DIM + c];
  }
  float o;
  if (cn > 0) o = acc * (1.0f / (float)cn) + bfuse[c];
  else        o = bout[c];
  out[(size_t)row * OUT_DIM + c] = o;
}

// ---------------------------------------------------------------------------
extern "C" void kernel_launch(void* const* d_in, const int* in_sizes, int n_in,
                              void* d_out, int out_size, void* d_ws, size_t ws_size,
                              hipStream_t stream) {
  const float* feat_user  = (const float*)d_in[0];
  // d_in[1] feat_item : dead (never reaches the output)
  const int*   src_clicks = (const int*)d_in[2];
  const int*   dst_clicks = (const int*)d_in[3];
  const int*   src_cb     = (const int*)d_in[4];
  const int*   dst_cb     = (const int*)d_in[5];
  const float* Win_user   = (const float*)d_in[6];
  const float* bin_user   = (const float*)d_in[7];
  // d_in[8..9] Win_item/bin_item : dead
  const float* W0_clicks  = (const float*)d_in[10];
  const float* b0_clicks  = (const float*)d_in[11];
  // d_in[12..15] W0_cb/b0_cb/W1_clicks/b1_clicks : dead
  const float* W1_cb      = (const float*)d_in[16];
  const float* b1_cb      = (const float*)d_in[17];
  const float* Wout       = (const float*)d_in[18];
  const float* bout       = (const float*)d_in[19];
  float* out = (float*)d_out;

  const size_t SZ  = (size_t)N_USER * HID * sizeof(float);           // 51.2 MB
  const size_t SZH = (size_t)N_USER * HID * sizeof(unsigned short);  // 25.6 MB
  const size_t SZZ = (size_t)N_USER * OUT_DIM * sizeof(float);       // 6.4 MB
  const size_t SZE = (size_t)2 * NC * CAPB * sizeof(uint32_t);       // 9.63 MB
  char* ws = (char*)d_ws;
  float* buf0          = (float*)ws;                   // h_i0 (gather-1 out)
  // tmp (coarse-binned records) aliases buf0: dead before gather-1 runs.
  uint32_t* tmp        = (uint32_t*)ws;                // [2][NC][CAPB]
  unsigned short* bh   = (unsigned short*)(ws + SZ);   // wh_u0 (bf16)
  float* z0            = (float*)(ws + SZ + SZH);      // h_i0 @ Wfuse
  // Bswz/bf0 overlap the z0 region: they are dead before gemm_z16 writes z0.
  unsigned short* Bswz = (unsigned short*)z0;                  // [64K] = 128 KB
  float* bf0v          = (float*)((char*)z0 + 131072);         // [128]
  float* Wf            = (float*)(ws + SZ + SZH + SZZ);        // [128,16]
  float* bf            = Wf + HID * OUT_DIM;                   // [16]
  int* cnt  = (int*)(bf + OUT_DIM);               // [2][100000] per-dst degree
  int* pos  = cnt + 2 * N_USER;                   // [2][100000] per-dst row beg
  int* gcur = pos + 2 * N_USER;                   // [2][NC] bucket fill counts
  uint32_t* ebuf = (uint32_t*)(gcur + 2 * NC + 12);  // [2][NC][CAPB] final

  const int G16 = N_USER / 16;                    // 6250
  const int GM  = (N_USER + 127) / 128;           // 782
  const int GP  = (N_EDGE + TILE - 1) / TILE;     // 245

  // --- 2-pass padded-bucket edge partition (both relations via y) ---
  hipMemsetAsync(gcur, 0, (size_t)2 * NC * sizeof(int), stream);
  part_coarse<<<dim3(GP, 2), 256, 0, stream>>>(src_clicks, dst_clicks,
                                               src_cb, dst_cb, gcur, tmp, N_EDGE);
  part_fine<<<dim3(NC, 2), 256, 0, stream>>>(tmp, gcur, ebuf, pos, cnt);

  // fused final projection: Wf = W1_cb @ Wout, bf = b1_cb @ Wout + bout
  make_wfuse<<<1, 256, 0, stream>>>(W1_cb, b1_cb, Wout, bout, Wf, bf);
  // fused input projection: Bswz = split/swizzled(Win_user @ W0_clicks),
  // bf0 = bin_user @ W0_clicks + b0_clicks
  make_wfuse0<<<128, 256, 0, stream>>>(Win_user, bin_user, W0_clicks, b0_clicks,
                                       Bswz, bf0v);

  // 1) wh_u0 = feat_user @ (Win@W0) + bf0  (split-bf16 MFMA) -> bh (bf16)
  gemm_feat_mfma<<<GM, 256, 0, stream>>>(feat_user, Bswz, bf0v, bh, N_USER);
  // 2) h_i0 = leaky(seg_mean over clicks)                    -> buf0 (fp32)
  gather_mean_bf16<<<G16, 256, 0, stream>>>(bh, pos, cnt, ebuf, buf0);
  // 3) z0 = h_i0 @ (W1_cb @ Wout)                            -> z0
  gemm_z16<<<G16, 256, 0, stream>>>(buf0, Wf, z0, N_ITEM);
  // 4) out = seg_mean(z0 over clicked_by) + bias select      -> out
  gather_mean16<<<G16, 256, 0, stream>>>(z0, pos + N_USER, cnt + N_USER,
                                         ebuf + (size_t)NC * CAPB, bf, bout, out);
}